// Round 9
// baseline (3418.971 us; speedup 1.0000x reference)
//
#include <hip/hip_runtime.h>

// Fused 2-layer GRU scan. B=256,T=1024,F=64,U=128.
// R8 post-mortem: 2 waves/SIMD achieved but 128 arch + 144 AGPR = 272 > 256
// per-wave cap -> weight frags spilled mid-loop (asm pins only bind at the
// asm site). R9: (1) re-pin all 36 weight frags at EVERY loop iteration so
// they are loop-carried acc-class values; (2) rotating distance-1 xw
// prefetch (6 regs + ptr bump) replacing dual-parity distance-2 (12 regs +
// per-parity 64-bit addr math) to shrink the arch working set to ~100.
// Structure: 16 blocks x 512 thr (8 waves, 2/SIMD), wave owns 16 unit cols,
// weights U1/W2/U2 in AGPR, xw=x@W1+biases precomputed coalesced in d_ws,
// layer2 one step delayed => single LDS-only barrier/step.

#define TT 1024
#define FF 64
#define G3 384
#define XW_BYTES (1024ull * 384 * 256 * 2)

typedef __attribute__((ext_vector_type(8))) __bf16 bf16x8;
typedef __attribute__((ext_vector_type(4))) float f32x4;
typedef __attribute__((ext_vector_type(4))) int i32x4;

#define MFMA(a, b, c) __builtin_amdgcn_mfma_f32_16x16x32_bf16((a), (b), (c), 0, 0, 0)
#define BCAST(w) __builtin_bit_cast(bf16x8, w)

__device__ __forceinline__ float sigf(float x) {
    return __builtin_amdgcn_rcpf(1.0f + __expf(-x));
}

__device__ __forceinline__ f32x4 unpackv(uint2 v) {
    f32x4 o;
    o[0] = __uint_as_float(v.x << 16);
    o[1] = __uint_as_float(v.x & 0xFFFF0000u);
    o[2] = __uint_as_float(v.y << 16);
    o[3] = __uint_as_float(v.y & 0xFFFF0000u);
    return o;
}

// ---- prepass: ws uint2 index = ((t*16+rb)*3+g)*512 + cg*64 + lane ---------
// slot holds batch rows quad*4..+3, unit col cg*16+lc, bf16x4 packed.
// Gates z,r: input+recurrent biases folded; gate h: input bias only.
__global__ void xw_prepass(
    const float* __restrict__ x, const float* __restrict__ W1,
    const float* __restrict__ b1, unsigned short* __restrict__ ws)
{
    const int tid = threadIdx.x, wave = tid >> 6, lane = tid & 63;
    const int quad = lane >> 4, lc = lane & 15;
    const int rb = blockIdx.x;              // row block (16 rows)
    const int t0 = blockIdx.y * 4;          // 4 time steps per block
    const int t  = t0 + wave;

    __shared__ __align__(16) float xs[16][4][72];
    {
        const int r = tid >> 4;
        const int c = (tid & 15) * 16;
        const float* src = x + ((size_t)(rb * 16 + r) * TT + t0) * FF + c;
#pragma unroll
        for (int k = 0; k < 16; k += 4) {
            f32x4 v = *(const f32x4*)(src + k);
            int cc = c + k;
            *(f32x4*)&xs[r][cc >> 6][cc & 63] = v;
        }
    }
    __syncthreads();

    const float* xr_ = &xs[lc][wave][0];
    f32x4 u0 = *(const f32x4*)(xr_ + quad * 8);
    f32x4 u1 = *(const f32x4*)(xr_ + quad * 8 + 4);
    f32x4 u2 = *(const f32x4*)(xr_ + 32 + quad * 8);
    f32x4 u3 = *(const f32x4*)(xr_ + 36 + quad * 8);
    bf16x8 xa0, xa1;
#pragma unroll
    for (int j = 0; j < 4; j++) {
        xa0[j] = (__bf16)u0[j]; xa0[j + 4] = (__bf16)u1[j];
        xa1[j] = (__bf16)u2[j]; xa1[j + 4] = (__bf16)u3[j];
    }

    uint2* wq = (uint2*)ws + ((size_t)t * 16 + rb) * 1536 + lane;
    for (int nt = 0; nt < 24; nt++) {
        const int g  = nt >> 3;
        const int cg = nt & 7;
        const int uc = cg * 16 + lc;
        float bi = b1[g * 128 + uc];
        if (g < 2) bi += b1[G3 + g * 128 + uc];   // fold recurrent bias (z,r)
        bf16x8 w0, w1v;
#pragma unroll
        for (int j = 0; j < 8; j++) {
            w0[j]  = (__bf16)W1[(quad * 8 + j) * G3 + g * 128 + uc];
            w1v[j] = (__bf16)W1[(32 + quad * 8 + j) * G3 + g * 128 + uc];
        }
        f32x4 acc = {bi, bi, bi, bi};
        acc = MFMA(xa0, w0, acc);
        acc = MFMA(xa1, w1v, acc);
        unsigned int s0 = __builtin_bit_cast(unsigned short, (__bf16)acc[0]);
        unsigned int s1 = __builtin_bit_cast(unsigned short, (__bf16)acc[1]);
        unsigned int s2 = __builtin_bit_cast(unsigned short, (__bf16)acc[2]);
        unsigned int s3 = __builtin_bit_cast(unsigned short, (__bf16)acc[3]);
        uint2 st;
        st.x = s0 | (s1 << 16);
        st.y = s2 | (s3 << 16);
        wq[(size_t)(g * 8 + cg) * 64] = st;   // 512B contiguous per wave
    }
}

// ---- persistent scan kernel -----------------------------------------------
template <bool PRE>
__global__ __launch_bounds__(512, 2) void gru_persist(
    const float* __restrict__ x,  const float* __restrict__ W1,
    const float* __restrict__ U1, const float* __restrict__ b1,
    const float* __restrict__ W2, const float* __restrict__ U2,
    const float* __restrict__ b2, const unsigned short* __restrict__ xw,
    float* __restrict__ out)
{
    const int tid  = threadIdx.x;
    const int wave = tid >> 6;          // 0..7, owns unit cols [16w,16w+16)
    const int lane = tid & 63;
    const int quad = lane >> 4;
    const int lc   = lane & 15;
    const int u    = wave * 16 + lc;
    const int row0 = blockIdx.x * 16;

    __shared__ __align__(16) __bf16 h1s[2][16][136];
    __shared__ __align__(16) __bf16 h2s[2][16][136];
    for (int i = tid; i < 2 * 16 * 136; i += 512) {
        ((__bf16*)h1s)[i] = (__bf16)0.f;
        ((__bf16*)h2s)[i] = (__bf16)0.f;
    }

    // ---- weight B-frags: 36 frags = 144 regs, AGPR resident ----
    i32x4 U1B[3][4], W2B[3][4], U2B[3][4];
    i32x4 W1B[3][2];
#pragma unroll
    for (int g = 0; g < 3; g++) {
#pragma unroll
        for (int kt = 0; kt < 4; kt++) {
            bf16x8 a, b, c;
#pragma unroll
            for (int j = 0; j < 8; j++) {
                int k = (kt * 32 + quad * 8 + j) * G3 + g * 128 + u;
                a[j] = (__bf16)U1[k];
                b[j] = (__bf16)W2[k];
                c[j] = (__bf16)U2[k];
            }
            U1B[g][kt] = __builtin_bit_cast(i32x4, a);
            W2B[g][kt] = __builtin_bit_cast(i32x4, b);
            U2B[g][kt] = __builtin_bit_cast(i32x4, c);
        }
        if constexpr (!PRE) {
#pragma unroll
            for (int kt = 0; kt < 2; kt++) {
                bf16x8 a;
#pragma unroll
                for (int j = 0; j < 8; j++)
                    a[j] = (__bf16)W1[(kt * 32 + quad * 8 + j) * G3 + g * 128 + u];
                W1B[g][kt] = __builtin_bit_cast(i32x4, a);
            }
        }
    }
#define PIN_WEIGHTS()                                                          \
    _Pragma("unroll") for (int g_ = 0; g_ < 3; g_++)                           \
        _Pragma("unroll") for (int kt_ = 0; kt_ < 4; kt_++)                    \
            asm volatile("" : "+a"(U1B[g_][kt_]), "+a"(W2B[g_][kt_]),          \
                              "+a"(U2B[g_][kt_]));
    PIN_WEIGHTS()
    if constexpr (!PRE) {
#pragma unroll
        for (int g = 0; g < 3; g++)
#pragma unroll
            for (int kt = 0; kt < 2; kt++)
                asm volatile("" : "+v"(W1B[g][kt]));
    }

    // ---- biases (zero here; honored) ----
    float c1z = 0.f, c1r = 0.f, b1ih = 0.f;
    if constexpr (!PRE) {
        c1z  = b1[u] + b1[G3 + u];
        c1r  = b1[128 + u] + b1[G3 + 128 + u];
        b1ih = b1[256 + u];
    }
    const float b1rh = b1[G3 + 256 + u];
    const float c2z  = b2[u] + b2[G3 + u];
    const float c2r  = b2[128 + u] + b2[G3 + 128 + u];
    const float b2ih = b2[256 + u];
    const float b2rh = b2[G3 + 256 + u];

    // ---- xw rotating prefetch, distance 1 ------------------------------
    // uint2 index = ((t*16+rb)*3+g)*512 + wave*64 + lane; stride/t = 24576.
    const uint2* xqb = (const uint2*)xw + (size_t)blockIdx.x * 1536
                       + wave * 64 + lane;
    uint2 xwv[3];                 // holds xw(t) at each step top
    const uint2* xp = xqb + 24576;  // points at xw(t+1)
    if constexpr (PRE) {
#pragma unroll
        for (int g = 0; g < 3; g++) xwv[g] = xqb[(size_t)g * 512];
    }
    const float* xrow = nullptr;
    if constexpr (!PRE) xrow = x + (size_t)(row0 + lc) * (TT * FF) + quad * 8;

    float h1c[4] = {0.f, 0.f, 0.f, 0.f};
    float h2c[4] = {0.f, 0.f, 0.f, 0.f};

    __syncthreads();

#define STEP(T, PAR)                                                           \
    {                                                                          \
        bf16x8 A[4];                                                           \
        _Pragma("unroll") for (int kt = 0; kt < 4; kt++)                       \
            A[kt] = *(const bf16x8*)&h1s[PAR ^ 1][lc][kt * 32 + quad * 8];     \
        f32x4 z1, r1, rh1, xh1;                                                \
        bf16x8 xa0, xa1;                                                       \
        if constexpr (PRE) {                                                   \
            z1  = unpackv(xwv[0]);    /* xz incl. both biases */               \
            r1  = unpackv(xwv[1]);                                             \
            xh1 = unpackv(xwv[2]);    /* xh incl. input bias  */               \
            rh1 = (f32x4){b1rh, b1rh, b1rh, b1rh};                             \
            if ((T) + 1 < TT) {                                                \
                xwv[0] = xp[0];                                                \
                xwv[1] = xp[512];                                              \
                xwv[2] = xp[1024];                                             \
            }                                                                  \
            xp += 24576;                                                       \
        } else {                                                               \
            const float* px = xrow + (size_t)(T) * FF;                         \
            f32x4 u0 = *(const f32x4*)px;                                      \
            f32x4 u1 = *(const f32x4*)(px + 4);                                \
            f32x4 u2 = *(const f32x4*)(px + 32);                               \
            f32x4 u3 = *(const f32x4*)(px + 36);                               \
            _Pragma("unroll") for (int j = 0; j < 4; j++) {                    \
                xa0[j] = (__bf16)u0[j]; xa0[j + 4] = (__bf16)u1[j];            \
                xa1[j] = (__bf16)u2[j]; xa1[j + 4] = (__bf16)u3[j];            \
            }                                                                  \
            z1  = (f32x4){c1z, c1z, c1z, c1z};                                 \
            r1  = (f32x4){c1r, c1r, c1r, c1r};                                 \
            rh1 = (f32x4){b1rh, b1rh, b1rh, b1rh};                             \
            xh1 = (f32x4){b1ih, b1ih, b1ih, b1ih};                             \
            z1  = MFMA(xa0, BCAST(W1B[0][0]), z1);                             \
            z1  = MFMA(xa1, BCAST(W1B[0][1]), z1);                             \
            r1  = MFMA(xa0, BCAST(W1B[1][0]), r1);                             \
            r1  = MFMA(xa1, BCAST(W1B[1][1]), r1);                             \
            xh1 = MFMA(xa0, BCAST(W1B[2][0]), xh1);                            \
            xh1 = MFMA(xa1, BCAST(W1B[2][1]), xh1);                            \
        }                                                                      \
        _Pragma("unroll") for (int kt = 0; kt < 4; kt++) {                     \
            z1  = MFMA(A[kt], BCAST(U1B[0][kt]), z1);                          \
            r1  = MFMA(A[kt], BCAST(U1B[1][kt]), r1);                          \
            rh1 = MFMA(A[kt], BCAST(U1B[2][kt]), rh1);                         \
        }                                                                      \
        f32x4 z2  = {c2z, c2z, c2z, c2z};                                      \
        f32x4 r2  = {c2r, c2r, c2r, c2r};                                      \
        f32x4 xh2 = {b2ih, b2ih, b2ih, b2ih};                                  \
        f32x4 rh2 = {b2rh, b2rh, b2rh, b2rh};                                  \
        _Pragma("unroll") for (int kt = 0; kt < 4; kt++) {                     \
            z2  = MFMA(A[kt], BCAST(W2B[0][kt]), z2);                          \
            r2  = MFMA(A[kt], BCAST(W2B[1][kt]), r2);                          \
            xh2 = MFMA(A[kt], BCAST(W2B[2][kt]), xh2);                         \
        }                                                                      \
        _Pragma("unroll") for (int kt = 0; kt < 4; kt++)                       \
            A[kt] = *(const bf16x8*)&h2s[PAR][lc][kt * 32 + quad * 8];         \
        _Pragma("unroll") for (int kt = 0; kt < 4; kt++) {                     \
            z2  = MFMA(A[kt], BCAST(U2B[0][kt]), z2);                          \
            r2  = MFMA(A[kt], BCAST(U2B[1][kt]), r2);                          \
            rh2 = MFMA(A[kt], BCAST(U2B[2][kt]), rh2);                         \
        }                                                                      \
        _Pragma("unroll") for (int i = 0; i < 4; i++) {                        \
            float zf = sigf(z1[i]);                                            \
            float rf = sigf(r1[i]);                                            \
            float hh = fmaxf(xh1[i] + rf * rh1[i], 0.f);                       \
            h1c[i] = fmaf(zf, h1c[i] - hh, hh);                                \
            h1s[PAR][quad * 4 + i][u] = (__bf16)h1c[i];                        \
        }                                                                      \
        if ((T) > 0) {                                                         \
            _Pragma("unroll") for (int i = 0; i < 4; i++) {                    \
                float zf = sigf(z2[i]);                                        \
                float rf = sigf(r2[i]);                                        \
                float hh = fmaxf(xh2[i] + rf * rh2[i], 0.f);                   \
                h2c[i] = fmaf(zf, h2c[i] - hh, hh);                            \
            }                                                                  \
        }                                                                      \
        _Pragma("unroll") for (int i = 0; i < 4; i++)                          \
            h2s[PAR ^ 1][quad * 4 + i][u] = (__bf16)h2c[i];                    \
        asm volatile("s_waitcnt lgkmcnt(0)\n\ts_barrier" ::: "memory");        \
    }

    for (int t = 0; t < TT; t += 2) {
        PIN_WEIGHTS()            // loop-carried acc-class: forbid mid-loop spill
        STEP(t, 0)
        STEP(t + 1, 1)
    }
#undef STEP

    // Epilogue: h2(TT-1) from h1(TT-1) (h1s[1]) and h2(TT-2) (h2s[0])
    {
        f32x4 z2  = {c2z, c2z, c2z, c2z};
        f32x4 r2  = {c2r, c2r, c2r, c2r};
        f32x4 xh2 = {b2ih, b2ih, b2ih, b2ih};
        f32x4 rh2 = {b2rh, b2rh, b2rh, b2rh};
#pragma unroll
        for (int kt = 0; kt < 4; kt++) {
            bf16x8 a1 = *(const bf16x8*)&h1s[1][lc][kt * 32 + quad * 8];
            bf16x8 a2 = *(const bf16x8*)&h2s[0][lc][kt * 32 + quad * 8];
            z2  = MFMA(a1, BCAST(W2B[0][kt]), z2);
            r2  = MFMA(a1, BCAST(W2B[1][kt]), r2);
            xh2 = MFMA(a1, BCAST(W2B[2][kt]), xh2);
            z2  = MFMA(a2, BCAST(U2B[0][kt]), z2);
            r2  = MFMA(a2, BCAST(U2B[1][kt]), r2);
            rh2 = MFMA(a2, BCAST(U2B[2][kt]), rh2);
        }
#pragma unroll
        for (int i = 0; i < 4; i++) {
            float zf = sigf(z2[i]);
            float rf = sigf(r2[i]);
            float hh = fmaxf(xh2[i] + rf * rh2[i], 0.f);
            h2c[i] = fmaf(zf, h2c[i] - hh, hh);
        }
    }

    // out = [x = h2(T-1), state1 = h1(T-1), state2 = h2(T-1)]
#pragma unroll
    for (int i = 0; i < 4; i++) {
        int r = row0 + quad * 4 + i;
        out[(size_t)r * 128 + u]         = h2c[i];
        out[32768 + (size_t)r * 128 + u] = h1c[i];
        out[65536 + (size_t)r * 128 + u] = h2c[i];
    }
#undef PIN_WEIGHTS
}

extern "C" void kernel_launch(void* const* d_in, const int* in_sizes, int n_in,
                              void* d_out, int out_size, void* d_ws, size_t ws_size,
                              hipStream_t stream) {
    const float* x  = (const float*)d_in[0];
    const float* W1 = (const float*)d_in[1];
    const float* U1 = (const float*)d_in[2];
    const float* b1 = (const float*)d_in[3];
    const float* W2 = (const float*)d_in[4];
    const float* U2 = (const float*)d_in[5];
    const float* b2 = (const float*)d_in[6];
    float* out = (float*)d_out;

    if (ws_size >= XW_BYTES) {
        unsigned short* ws = (unsigned short*)d_ws;
        xw_prepass<<<dim3(16, 256), dim3(256), 0, stream>>>(x, W1, b1, ws);
        gru_persist<true><<<dim3(16), dim3(512), 0, stream>>>(
            x, W1, U1, b1, W2, U2, b2, ws, out);
    } else {
        gru_persist<false><<<dim3(16), dim3(512), 0, stream>>>(
            x, W1, U1, b1, W2, U2, b2, nullptr, out);
    }
}

// Round 10
// 2213.672 us; speedup vs baseline: 1.5445x; 1.5445x over previous
//
#include <hip/hip_runtime.h>

// Fused 2-layer GRU scan. B=256,T=1024,F=64,U=128.
// R8/R9 post-mortem: at 2 waves/SIMD the budget is 256 regs/wave and the
// compiler splits 128 arch + 128 AGPR. R8 pinned 144 regs "+a" -> 16 over ->
// mid-loop scratch spill (+750us). R9's per-loop re-pin made loop-carried
// copies (WRITE_SIZE 2336). R10: EXACT-FIT pin: 32 frags (128 regs) "+a"
// (U1B[z,r], W2B, U2B), U1B[h] (4 frags/16 regs) "+v"; pin once; rotating
// distance-1 xw prefetch (register-cheap). Also: VALUBusy includes MFMA on
// gfx94x formulas -- R7's pure-VALU is ~800cyc/step, so 2 waves/SIMD should
// overlap to step ~1800-2100cyc.
// Structure: 16 blocks x 512 thr (8 waves, 2/SIMD), wave owns 16 unit cols,
// xw=x@W1+biases precomputed coalesced in d_ws, layer2 one step delayed =>
// single LDS-only barrier/step.

#define TT 1024
#define FF 64
#define G3 384
#define XW_BYTES (1024ull * 384 * 256 * 2)

typedef __attribute__((ext_vector_type(8))) __bf16 bf16x8;
typedef __attribute__((ext_vector_type(4))) float f32x4;
typedef __attribute__((ext_vector_type(4))) int i32x4;

#define MFMA(a, b, c) __builtin_amdgcn_mfma_f32_16x16x32_bf16((a), (b), (c), 0, 0, 0)
#define BCAST(w) __builtin_bit_cast(bf16x8, w)

__device__ __forceinline__ float sigf(float x) {
    return __builtin_amdgcn_rcpf(1.0f + __expf(-x));
}

__device__ __forceinline__ f32x4 unpackv(uint2 v) {
    f32x4 o;
    o[0] = __uint_as_float(v.x << 16);
    o[1] = __uint_as_float(v.x & 0xFFFF0000u);
    o[2] = __uint_as_float(v.y << 16);
    o[3] = __uint_as_float(v.y & 0xFFFF0000u);
    return o;
}

// ---- prepass: ws uint2 index = ((t*16+rb)*3+g)*512 + cg*64 + lane ---------
// slot holds batch rows quad*4..+3, unit col cg*16+lc, bf16x4 packed.
// Gates z,r: input+recurrent biases folded; gate h: input bias only.
__global__ void xw_prepass(
    const float* __restrict__ x, const float* __restrict__ W1,
    const float* __restrict__ b1, unsigned short* __restrict__ ws)
{
    const int tid = threadIdx.x, wave = tid >> 6, lane = tid & 63;
    const int quad = lane >> 4, lc = lane & 15;
    const int rb = blockIdx.x;              // row block (16 rows)
    const int t0 = blockIdx.y * 4;          // 4 time steps per block
    const int t  = t0 + wave;

    __shared__ __align__(16) float xs[16][4][72];
    {
        const int r = tid >> 4;
        const int c = (tid & 15) * 16;
        const float* src = x + ((size_t)(rb * 16 + r) * TT + t0) * FF + c;
#pragma unroll
        for (int k = 0; k < 16; k += 4) {
            f32x4 v = *(const f32x4*)(src + k);
            int cc = c + k;
            *(f32x4*)&xs[r][cc >> 6][cc & 63] = v;
        }
    }
    __syncthreads();

    const float* xr_ = &xs[lc][wave][0];
    f32x4 u0 = *(const f32x4*)(xr_ + quad * 8);
    f32x4 u1 = *(const f32x4*)(xr_ + quad * 8 + 4);
    f32x4 u2 = *(const f32x4*)(xr_ + 32 + quad * 8);
    f32x4 u3 = *(const f32x4*)(xr_ + 36 + quad * 8);
    bf16x8 xa0, xa1;
#pragma unroll
    for (int j = 0; j < 4; j++) {
        xa0[j] = (__bf16)u0[j]; xa0[j + 4] = (__bf16)u1[j];
        xa1[j] = (__bf16)u2[j]; xa1[j + 4] = (__bf16)u3[j];
    }

    uint2* wq = (uint2*)ws + ((size_t)t * 16 + rb) * 1536 + lane;
    for (int nt = 0; nt < 24; nt++) {
        const int g  = nt >> 3;
        const int cg = nt & 7;
        const int uc = cg * 16 + lc;
        float bi = b1[g * 128 + uc];
        if (g < 2) bi += b1[G3 + g * 128 + uc];   // fold recurrent bias (z,r)
        bf16x8 w0, w1v;
#pragma unroll
        for (int j = 0; j < 8; j++) {
            w0[j]  = (__bf16)W1[(quad * 8 + j) * G3 + g * 128 + uc];
            w1v[j] = (__bf16)W1[(32 + quad * 8 + j) * G3 + g * 128 + uc];
        }
        f32x4 acc = {bi, bi, bi, bi};
        acc = MFMA(xa0, w0, acc);
        acc = MFMA(xa1, w1v, acc);
        unsigned int s0 = __builtin_bit_cast(unsigned short, (__bf16)acc[0]);
        unsigned int s1 = __builtin_bit_cast(unsigned short, (__bf16)acc[1]);
        unsigned int s2 = __builtin_bit_cast(unsigned short, (__bf16)acc[2]);
        unsigned int s3 = __builtin_bit_cast(unsigned short, (__bf16)acc[3]);
        uint2 st;
        st.x = s0 | (s1 << 16);
        st.y = s2 | (s3 << 16);
        wq[(size_t)(g * 8 + cg) * 64] = st;   // 512B contiguous per wave
    }
}

// ---- persistent scan kernel -----------------------------------------------
template <bool PRE>
__global__ __launch_bounds__(512, 2) void gru_persist(
    const float* __restrict__ x,  const float* __restrict__ W1,
    const float* __restrict__ U1, const float* __restrict__ b1,
    const float* __restrict__ W2, const float* __restrict__ U2,
    const float* __restrict__ b2, const unsigned short* __restrict__ xw,
    float* __restrict__ out)
{
    const int tid  = threadIdx.x;
    const int wave = tid >> 6;          // 0..7, owns unit cols [16w,16w+16)
    const int lane = tid & 63;
    const int quad = lane >> 4;
    const int lc   = lane & 15;
    const int u    = wave * 16 + lc;
    const int row0 = blockIdx.x * 16;

    __shared__ __align__(16) __bf16 h1s[2][16][136];
    __shared__ __align__(16) __bf16 h2s[2][16][136];
    for (int i = tid; i < 2 * 16 * 136; i += 512) {
        ((__bf16*)h1s)[i] = (__bf16)0.f;
        ((__bf16*)h2s)[i] = (__bf16)0.f;
    }

    // ---- weight B-frags: 36 frags = 144 regs ----
    i32x4 U1B[3][4], W2B[3][4], U2B[3][4];
    i32x4 W1B[3][2];
#pragma unroll
    for (int g = 0; g < 3; g++) {
#pragma unroll
        for (int kt = 0; kt < 4; kt++) {
            bf16x8 a, b, c;
#pragma unroll
            for (int j = 0; j < 8; j++) {
                int k = (kt * 32 + quad * 8 + j) * G3 + g * 128 + u;
                a[j] = (__bf16)U1[k];
                b[j] = (__bf16)W2[k];
                c[j] = (__bf16)U2[k];
            }
            U1B[g][kt] = __builtin_bit_cast(i32x4, a);
            W2B[g][kt] = __builtin_bit_cast(i32x4, b);
            U2B[g][kt] = __builtin_bit_cast(i32x4, c);
        }
        if constexpr (!PRE) {
#pragma unroll
            for (int kt = 0; kt < 2; kt++) {
                bf16x8 a;
#pragma unroll
                for (int j = 0; j < 8; j++)
                    a[j] = (__bf16)W1[(kt * 32 + quad * 8 + j) * G3 + g * 128 + u];
                W1B[g][kt] = __builtin_bit_cast(i32x4, a);
            }
        }
    }
    // EXACT-FIT class pins (once): 32 frags = 128 AGPR (the full file half at
    // 2 waves/SIMD); U1B[2] (h-gate, 16 regs) stays arch ("+v").
#pragma unroll
    for (int kt = 0; kt < 4; kt++) {
        asm volatile("" : "+a"(U1B[0][kt]), "+a"(U1B[1][kt]));
        asm volatile("" : "+a"(W2B[0][kt]), "+a"(W2B[1][kt]), "+a"(W2B[2][kt]));
        asm volatile("" : "+a"(U2B[0][kt]), "+a"(U2B[1][kt]), "+a"(U2B[2][kt]));
        asm volatile("" : "+v"(U1B[2][kt]));
    }
    if constexpr (!PRE) {
#pragma unroll
        for (int g = 0; g < 3; g++)
#pragma unroll
            for (int kt = 0; kt < 2; kt++)
                asm volatile("" : "+v"(W1B[g][kt]));
    }

    // ---- biases (zero here; honored) ----
    float c1z = 0.f, c1r = 0.f, b1ih = 0.f;
    if constexpr (!PRE) {
        c1z  = b1[u] + b1[G3 + u];
        c1r  = b1[128 + u] + b1[G3 + 128 + u];
        b1ih = b1[256 + u];
    }
    const float b1rh = b1[G3 + 256 + u];
    const float c2z  = b2[u] + b2[G3 + u];
    const float c2r  = b2[128 + u] + b2[G3 + 128 + u];
    const float b2ih = b2[256 + u];
    const float b2rh = b2[G3 + 256 + u];

    // ---- xw rotating prefetch, distance 1 ------------------------------
    // uint2 index = ((t*16+rb)*3+g)*512 + wave*64 + lane; stride/t = 24576.
    const uint2* xqb = (const uint2*)xw + (size_t)blockIdx.x * 1536
                       + wave * 64 + lane;
    uint2 xwv[3];                   // holds xw(t) at each step top
    const uint2* xp = xqb + 24576;  // points at xw(t+1)
    if constexpr (PRE) {
#pragma unroll
        for (int g = 0; g < 3; g++) xwv[g] = xqb[(size_t)g * 512];
    }
    const float* xrow = nullptr;
    if constexpr (!PRE) xrow = x + (size_t)(row0 + lc) * (TT * FF) + quad * 8;

    float h1c[4] = {0.f, 0.f, 0.f, 0.f};
    float h2c[4] = {0.f, 0.f, 0.f, 0.f};

    __syncthreads();

#define STEP(T, PAR)                                                           \
    {                                                                          \
        bf16x8 A[4];                                                           \
        _Pragma("unroll") for (int kt = 0; kt < 4; kt++)                       \
            A[kt] = *(const bf16x8*)&h1s[PAR ^ 1][lc][kt * 32 + quad * 8];     \
        f32x4 z1, r1, rh1, xh1;                                                \
        bf16x8 xa0, xa1;                                                       \
        if constexpr (PRE) {                                                   \
            z1  = unpackv(xwv[0]);    /* xz incl. both biases */               \
            r1  = unpackv(xwv[1]);                                             \
            xh1 = unpackv(xwv[2]);    /* xh incl. input bias  */               \
            rh1 = (f32x4){b1rh, b1rh, b1rh, b1rh};                             \
            if ((T) + 1 < TT) {                                                \
                xwv[0] = xp[0];                                                \
                xwv[1] = xp[512];                                              \
                xwv[2] = xp[1024];                                             \
            }                                                                  \
            xp += 24576;                                                       \
        } else {                                                               \
            const float* px = xrow + (size_t)(T) * FF;                         \
            f32x4 u0 = *(const f32x4*)px;                                      \
            f32x4 u1 = *(const f32x4*)(px + 4);                                \
            f32x4 u2 = *(const f32x4*)(px + 32);                               \
            f32x4 u3 = *(const f32x4*)(px + 36);                               \
            _Pragma("unroll") for (int j = 0; j < 4; j++) {                    \
                xa0[j] = (__bf16)u0[j]; xa0[j + 4] = (__bf16)u1[j];            \
                xa1[j] = (__bf16)u2[j]; xa1[j + 4] = (__bf16)u3[j];            \
            }                                                                  \
            z1  = (f32x4){c1z, c1z, c1z, c1z};                                 \
            r1  = (f32x4){c1r, c1r, c1r, c1r};                                 \
            rh1 = (f32x4){b1rh, b1rh, b1rh, b1rh};                             \
            xh1 = (f32x4){b1ih, b1ih, b1ih, b1ih};                             \
            z1  = MFMA(xa0, BCAST(W1B[0][0]), z1);                             \
            z1  = MFMA(xa1, BCAST(W1B[0][1]), z1);                             \
            r1  = MFMA(xa0, BCAST(W1B[1][0]), r1);                             \
            r1  = MFMA(xa1, BCAST(W1B[1][1]), r1);                             \
            xh1 = MFMA(xa0, BCAST(W1B[2][0]), xh1);                            \
            xh1 = MFMA(xa1, BCAST(W1B[2][1]), xh1);                            \
        }                                                                      \
        _Pragma("unroll") for (int kt = 0; kt < 4; kt++) {                     \
            z1  = MFMA(A[kt], BCAST(U1B[0][kt]), z1);                          \
            r1  = MFMA(A[kt], BCAST(U1B[1][kt]), r1);                          \
            rh1 = MFMA(A[kt], BCAST(U1B[2][kt]), rh1);                         \
        }                                                                      \
        f32x4 z2  = {c2z, c2z, c2z, c2z};                                      \
        f32x4 r2  = {c2r, c2r, c2r, c2r};                                      \
        f32x4 xh2 = {b2ih, b2ih, b2ih, b2ih};                                  \
        f32x4 rh2 = {b2rh, b2rh, b2rh, b2rh};                                  \
        _Pragma("unroll") for (int kt = 0; kt < 4; kt++) {                     \
            z2  = MFMA(A[kt], BCAST(W2B[0][kt]), z2);                          \
            r2  = MFMA(A[kt], BCAST(W2B[1][kt]), r2);                          \
            xh2 = MFMA(A[kt], BCAST(W2B[2][kt]), xh2);                         \
        }                                                                      \
        _Pragma("unroll") for (int kt = 0; kt < 4; kt++)                       \
            A[kt] = *(const bf16x8*)&h2s[PAR][lc][kt * 32 + quad * 8];         \
        _Pragma("unroll") for (int kt = 0; kt < 4; kt++) {                     \
            z2  = MFMA(A[kt], BCAST(U2B[0][kt]), z2);                          \
            r2  = MFMA(A[kt], BCAST(U2B[1][kt]), r2);                          \
            rh2 = MFMA(A[kt], BCAST(U2B[2][kt]), rh2);                         \
        }                                                                      \
        _Pragma("unroll") for (int i = 0; i < 4; i++) {                        \
            float zf = sigf(z1[i]);                                            \
            float rf = sigf(r1[i]);                                            \
            float hh = fmaxf(xh1[i] + rf * rh1[i], 0.f);                       \
            h1c[i] = fmaf(zf, h1c[i] - hh, hh);                                \
            h1s[PAR][quad * 4 + i][u] = (__bf16)h1c[i];                        \
        }                                                                      \
        if ((T) > 0) {                                                         \
            _Pragma("unroll") for (int i = 0; i < 4; i++) {                    \
                float zf = sigf(z2[i]);                                        \
                float rf = sigf(r2[i]);                                        \
                float hh = fmaxf(xh2[i] + rf * rh2[i], 0.f);                   \
                h2c[i] = fmaf(zf, h2c[i] - hh, hh);                            \
            }                                                                  \
        }                                                                      \
        _Pragma("unroll") for (int i = 0; i < 4; i++)                          \
            h2s[PAR ^ 1][quad * 4 + i][u] = (__bf16)h2c[i];                    \
        asm volatile("s_waitcnt lgkmcnt(0)\n\ts_barrier" ::: "memory");        \
    }

    for (int t = 0; t < TT; t += 2) {
        STEP(t, 0)
        STEP(t + 1, 1)
    }
#undef STEP

    // Epilogue: h2(TT-1) from h1(TT-1) (h1s[1]) and h2(TT-2) (h2s[0])
    {
        f32x4 z2  = {c2z, c2z, c2z, c2z};
        f32x4 r2  = {c2r, c2r, c2r, c2r};
        f32x4 xh2 = {b2ih, b2ih, b2ih, b2ih};
        f32x4 rh2 = {b2rh, b2rh, b2rh, b2rh};
#pragma unroll
        for (int kt = 0; kt < 4; kt++) {
            bf16x8 a1 = *(const bf16x8*)&h1s[1][lc][kt * 32 + quad * 8];
            bf16x8 a2 = *(const bf16x8*)&h2s[0][lc][kt * 32 + quad * 8];
            z2  = MFMA(a1, BCAST(W2B[0][kt]), z2);
            r2  = MFMA(a1, BCAST(W2B[1][kt]), r2);
            xh2 = MFMA(a1, BCAST(W2B[2][kt]), xh2);
            z2  = MFMA(a2, BCAST(U2B[0][kt]), z2);
            r2  = MFMA(a2, BCAST(U2B[1][kt]), r2);
            rh2 = MFMA(a2, BCAST(U2B[2][kt]), rh2);
        }
#pragma unroll
        for (int i = 0; i < 4; i++) {
            float zf = sigf(z2[i]);
            float rf = sigf(r2[i]);
            float hh = fmaxf(xh2[i] + rf * rh2[i], 0.f);
            h2c[i] = fmaf(zf, h2c[i] - hh, hh);
        }
    }

    // out = [x = h2(T-1), state1 = h1(T-1), state2 = h2(T-1)]
#pragma unroll
    for (int i = 0; i < 4; i++) {
        int r = row0 + quad * 4 + i;
        out[(size_t)r * 128 + u]         = h2c[i];
        out[32768 + (size_t)r * 128 + u] = h1c[i];
        out[65536 + (size_t)r * 128 + u] = h2c[i];
    }
}

extern "C" void kernel_launch(void* const* d_in, const int* in_sizes, int n_in,
                              void* d_out, int out_size, void* d_ws, size_t ws_size,
                              hipStream_t stream) {
    const float* x  = (const float*)d_in[0];
    const float* W1 = (const float*)d_in[1];
    const float* U1 = (const float*)d_in[2];
    const float* b1 = (const float*)d_in[3];
    const float* W2 = (const float*)d_in[4];
    const float* U2 = (const float*)d_in[5];
    const float* b2 = (const float*)d_in[6];
    float* out = (float*)d_out;

    if (ws_size >= XW_BYTES) {
        unsigned short* ws = (unsigned short*)d_ws;
        xw_prepass<<<dim3(16, 256), dim3(256), 0, stream>>>(x, W1, b1, ws);
        gru_persist<true><<<dim3(16), dim3(512), 0, stream>>>(
            x, W1, U1, b1, W2, U2, b2, ws, out);
    } else {
        gru_persist<false><<<dim3(16), dim3(512), 0, stream>>>(
            x, W1, U1, b1, W2, U2, b2, nullptr, out);
    }
}